// Round 2
// baseline (2730.698 us; speedup 1.0000x reference)
//
#include <hip/hip_runtime.h>
#include <hip/hip_bf16.h>
#include <stdint.h>

#define NN 50000
#define NE 400000
#define FN 32
#define FE 16
#define FG 16
#define H1 256
#define H2 128

typedef __hip_bfloat16 bf16;

__device__ __forceinline__ float bl(uint32_t u){ union{uint32_t i;float f;}v; v.i=u<<16; return v.f; }
__device__ __forceinline__ float bh(uint32_t u){ union{uint32_t i;float f;}v; v.i=u&0xffff0000u; return v.f; }

#define EPB 64   // edges per block in edge_all
#define AP  72   // LDS pitch (bf16 elems) per k-row: 144B -> 16B-aligned b128 reads

// ---------------- shared GEMM micro-tiles (VALU, A in LDS bf16 [k][i], B f32 in global) ----------------
__device__ __forceinline__ void gemm_acc_h1(const float* __restrict__ B, int K,
    const bf16* a_s, int cg, int rg, float (&acc)[4][16])
{
  for (int k = 0; k < K; k++){
    uint4 ar0 = *(const uint4*)&a_s[k*AP + rg*16];
    uint4 ar1 = *(const uint4*)&a_s[k*AP + rg*16 + 8];
    float a[16] = {bl(ar0.x),bh(ar0.x),bl(ar0.y),bh(ar0.y),bl(ar0.z),bh(ar0.z),bl(ar0.w),bh(ar0.w),
                   bl(ar1.x),bh(ar1.x),bl(ar1.y),bh(ar1.y),bl(ar1.z),bh(ar1.z),bl(ar1.w),bh(ar1.w)};
    float w0 = B[k*H1 + cg];
    float w1 = B[k*H1 + cg + 64];
    float w2 = B[k*H1 + cg + 128];
    float w3 = B[k*H1 + cg + 192];
    #pragma unroll
    for (int d = 0; d < 16; d++){
      acc[0][d] += a[d]*w0; acc[1][d] += a[d]*w1;
      acc[2][d] += a[d]*w2; acc[3][d] += a[d]*w3;
    }
  }
}

__device__ __forceinline__ void gemm_acc_h2(const float* __restrict__ B, int K,
    const bf16* a_s, int cg, int rg, float (&acc)[4][8])
{
  for (int k = 0; k < K; k++){
    uint4 ar = *(const uint4*)&a_s[k*AP + rg*8];
    float a[8] = {bl(ar.x),bh(ar.x),bl(ar.y),bh(ar.y),bl(ar.z),bh(ar.z),bl(ar.w),bh(ar.w)};
    float w0 = B[k*H2 + cg];
    float w1 = B[k*H2 + cg + 32];
    float w2 = B[k*H2 + cg + 64];
    float w3 = B[k*H2 + cg + 96];
    #pragma unroll
    for (int d = 0; d < 8; d++){
      acc[0][d] += a[d]*w0; acc[1][d] += a[d]*w1;
      acc[2][d] += a[d]*w2; acc[3][d] += a[d]*w3;
    }
  }
}

// ---------------- fused edge kernel: e1 (recompute), scatter1, e2, scatter2 ----------------
__global__ __launch_bounds__(256) void edge_all(
    const float* __restrict__ edges, const int* __restrict__ senders, const int* __restrict__ receivers,
    const float* __restrict__ We1, const float* __restrict__ be1,
    const float* __restrict__ We2, const float* __restrict__ be2,
    float* __restrict__ inc1, float* __restrict__ out1,
    float* __restrict__ inc2, float* __restrict__ out2,
    float* __restrict__ deg_in, float* __restrict__ deg_out,
    float* __restrict__ e2_out)
{
    __shared__ __align__(16) bf16 e1s[H1*AP];   // e1 tile, [k][i], 36.9 KB
    __shared__ __align__(16) float er[EPB*FE];  // staged edge rows (f32)
    __shared__ int rs[EPB], ss[EPB];
    const int t = threadIdx.x;
    const long e0 = (long)blockIdx.x * EPB;

    // stage 64 edge rows (64*16 f32 = 4 KB = 256 float4), coalesced
    {
      const float4* src = (const float4*)(edges + e0*FE);
      float4 v = src[t];
      int b = t*4;
      er[b] = v.x; er[b+1] = v.y; er[b+2] = v.z; er[b+3] = v.w;
    }
    if (t < EPB)          rs[t]     = receivers[e0 + t];
    else if (t < 2*EPB)   ss[t-EPB] = senders[e0 + t - EPB];
    __syncthreads();

    // e1 tile: thread t owns column k=t for all 64 edges
    {
      float w[FE];
      #pragma unroll
      for (int c = 0; c < FE; c++) w[c] = We1[c*H1 + t];
      const float bk = be1[t];
      for (int i = 0; i < EPB; i++){
        const float4* e4 = (const float4*)&er[i*FE];
        float4 a0 = e4[0], a1 = e4[1], a2 = e4[2], a3 = e4[3];
        float acc = bk;
        acc += a0.x*w[0] + a0.y*w[1] + a0.z*w[2] + a0.w*w[3];
        acc += a1.x*w[4] + a1.y*w[5] + a1.z*w[6] + a1.w*w[7];
        acc += a2.x*w[8] + a2.y*w[9] + a2.z*w[10]+ a2.w*w[11];
        acc += a3.x*w[12]+ a3.y*w[13]+ a3.z*w[14]+ a3.w*w[15];
        e1s[t*AP + i] = __float2bfloat16(fmaxf(acc, 0.f));
      }
    }
    __syncthreads();

    // scatter e1 into inc1/out1 (lanes = feature k -> coalesced atomics)
    for (int i = 0; i < EPB; i++){
      float v = (float)e1s[t*AP + i];
      atomicAdd(&inc1[(long)rs[i]*H1 + t], v);
      atomicAdd(&out1[(long)ss[i]*H1 + t], v);
    }
    if (t < EPB)        atomicAdd(&deg_in [rs[t]],     1.0f);
    else if (t < 2*EPB) atomicAdd(&deg_out[ss[t-EPB]], 1.0f);

    // e2 = relu(e1 @ We2 + be2): 64x128 tile, 4 cols x 8 rows per thread
    const int cg = t & 31, rg = t >> 5;
    float acc[4][8];
    #pragma unroll
    for (int c = 0; c < 4; c++)
      #pragma unroll
      for (int d = 0; d < 8; d++) acc[c][d] = 0.f;

    gemm_acc_h2(We2, H1, e1s, cg, rg, acc);

    #pragma unroll
    for (int c = 0; c < 4; c++){
      const int j = cg + 32*c;
      const float b = be2[j];
      #pragma unroll
      for (int d = 0; d < 8; d++){
        const int i = rg*8 + d;
        float v = fmaxf(acc[c][d] + b, 0.f);
        e2_out[(e0 + i)*H2 + j] = v;
        atomicAdd(&inc2[(long)rs[i]*H2 + j], v);
        atomicAdd(&out2[(long)ss[i]*H2 + j], v);
      }
    }
}

// ---------------- node block 1: n1 = relu(nodes@Wn1 + inc1@Win1 + out1@Wout1 + bn1) ----------------
__global__ __launch_bounds__(256) void node1_kernel(
    const float* __restrict__ nodes,
    const float* __restrict__ inc1, const float* __restrict__ out1,
    const float* __restrict__ deg_in, const float* __restrict__ deg_out,
    const float* __restrict__ Wn1, const float* __restrict__ Win1, const float* __restrict__ Wout1,
    const float* __restrict__ bn1,
    bf16* __restrict__ n1, float* __restrict__ n1_cs)
{
    __shared__ __align__(16) bf16 a_s[H1*AP];
    const int t = threadIdx.x;
    const long n0 = (long)blockIdx.x * 64;
    const int cg = t & 63, rg = t >> 6;
    float acc[4][16];
    #pragma unroll
    for (int c = 0; c < 4; c++)
      #pragma unroll
      for (int d = 0; d < 16; d++) acc[c][d] = 0.f;

    // phase 1: A = inc1/deg_in  (K=256), B = Win1
    for (int r = 0; r < 64; r++){
      long n = n0 + r; float v = 0.f;
      if (n < NN){
        float rd = 1.f / fmaxf(deg_in[n], 1.f);
        v = inc1[n*H1 + t] * rd;
      }
      a_s[t*AP + r] = __float2bfloat16(v);
    }
    __syncthreads();
    gemm_acc_h1(Win1, H1, a_s, cg, rg, acc);
    __syncthreads();

    // phase 2: A = out1/deg_out (K=256), B = Wout1
    for (int r = 0; r < 64; r++){
      long n = n0 + r; float v = 0.f;
      if (n < NN){
        float rd = 1.f / fmaxf(deg_out[n], 1.f);
        v = out1[n*H1 + t] * rd;
      }
      a_s[t*AP + r] = __float2bfloat16(v);
    }
    __syncthreads();
    gemm_acc_h1(Wout1, H1, a_s, cg, rg, acc);
    __syncthreads();

    // phase 3: A = nodes (K=32), B = Wn1
    for (int rr = 0; rr < 8; rr++){
      int i = rr*8 + (t >> 5);
      long n = n0 + i;
      float v = (n < NN) ? nodes[n*FN + (t & 31)] : 0.f;
      a_s[(t & 31)*AP + i] = __float2bfloat16(v);
    }
    __syncthreads();
    gemm_acc_h1(Wn1, FN, a_s, cg, rg, acc);

    #pragma unroll
    for (int c = 0; c < 4; c++){
      const int j = cg + 64*c;
      const float b = bn1[j];
      float csum = 0.f;
      #pragma unroll
      for (int d = 0; d < 16; d++){
        long n = n0 + rg*16 + d;
        if (n < NN){
          float v = fmaxf(acc[c][d] + b, 0.f);
          n1[n*H1 + j] = __float2bfloat16(v);
          csum += v;
        }
      }
      atomicAdd(&n1_cs[j], csum);
    }
}

// ---------------- node block 2: n2 = relu(n1@Wn2 + inc2@Win2 + out2@Wout2 + bn2) ----------------
__global__ __launch_bounds__(256) void node2_kernel(
    const bf16* __restrict__ n1,
    const float* __restrict__ inc2, const float* __restrict__ out2,
    const float* __restrict__ deg_in, const float* __restrict__ deg_out,
    const float* __restrict__ Wn2, const float* __restrict__ Win2, const float* __restrict__ Wout2,
    const float* __restrict__ bn2,
    float* __restrict__ n2_out, float* __restrict__ n2_cs)
{
    __shared__ __align__(16) bf16 a_s[H1*AP];
    const int t = threadIdx.x;
    const long n0 = (long)blockIdx.x * 64;
    const int cg = t & 31, rg = t >> 5;
    float acc[4][8];
    #pragma unroll
    for (int c = 0; c < 4; c++)
      #pragma unroll
      for (int d = 0; d < 8; d++) acc[c][d] = 0.f;

    // phase 1: A = n1 (K=256), B = Wn2
    for (int r = 0; r < 64; r++){
      long n = n0 + r;
      float v = (n < NN) ? (float)n1[n*H1 + t] : 0.f;
      a_s[t*AP + r] = __float2bfloat16(v);
    }
    __syncthreads();
    gemm_acc_h2(Wn2, H1, a_s, cg, rg, acc);
    __syncthreads();

    // phase 2: A = inc2/deg_in (K=128), B = Win2
    for (int rr = 0; rr < 32; rr++){
      int i = rr*2 + (t >> 7);
      long n = n0 + i; float v = 0.f;
      if (n < NN){
        float rd = 1.f / fmaxf(deg_in[n], 1.f);
        v = inc2[n*H2 + (t & 127)] * rd;
      }
      a_s[(t & 127)*AP + i] = __float2bfloat16(v);
    }
    __syncthreads();
    gemm_acc_h2(Win2, H2, a_s, cg, rg, acc);
    __syncthreads();

    // phase 3: A = out2/deg_out (K=128), B = Wout2
    for (int rr = 0; rr < 32; rr++){
      int i = rr*2 + (t >> 7);
      long n = n0 + i; float v = 0.f;
      if (n < NN){
        float rd = 1.f / fmaxf(deg_out[n], 1.f);
        v = out2[n*H2 + (t & 127)] * rd;
      }
      a_s[(t & 127)*AP + i] = __float2bfloat16(v);
    }
    __syncthreads();
    gemm_acc_h2(Wout2, H2, a_s, cg, rg, acc);

    #pragma unroll
    for (int c = 0; c < 4; c++){
      const int j = cg + 32*c;
      const float b = bn2[j];
      float csum = 0.f;
      #pragma unroll
      for (int d = 0; d < 8; d++){
        long n = n0 + rg*8 + d;
        if (n < NN){
          float v = fmaxf(acc[c][d] + b, 0.f);
          n2_out[n*H2 + j] = v;
          csum += v;
        }
      }
      atomicAdd(&n2_cs[j], csum);
    }
}

// ---------------- column-sum reduction over [rows, W] f32 (atomic into dst[W]) ----------------
__global__ __launch_bounds__(256) void colsum(const float* __restrict__ src, int rows, int W,
                                              float* __restrict__ dst)
{
    const int t = threadIdx.x;
    const int j = t % W;
    const int rsub = t / W;
    const int rpb = 256 / W;
    float s = 0.f;
    for (long r = (long)blockIdx.x * rpb + rsub; r < rows; r += (long)gridDim.x * rpb)
      s += src[r*W + j];
    atomicAdd(&dst[j], s);
}

// ---------------- global updates ----------------
__global__ void u1_kernel(const float* __restrict__ gu, const float* __restrict__ Wu1,
    const float* __restrict__ Wgn1, const float* __restrict__ Wge1, const float* __restrict__ bu1,
    const float* __restrict__ n1_cs, const float* __restrict__ e1_cs, float* __restrict__ u1v)
{
    const int j = threadIdx.x;
    float acc = bu1[j];
    #pragma unroll
    for (int k = 0; k < FG; k++) acc += gu[k] * Wu1[k*H1 + j];
    for (int k = 0; k < H1; k++) acc += (n1_cs[k] * (1.f/NN)) * Wgn1[k*H1 + j];
    for (int k = 0; k < H1; k++) acc += (e1_cs[k] * (1.f/NE)) * Wge1[k*H1 + j];
    u1v[j] = fmaxf(acc, 0.f);
}

__global__ void u2_kernel(const float* __restrict__ u1v, const float* __restrict__ Wu2,
    const float* __restrict__ Wgn2, const float* __restrict__ Wge2, const float* __restrict__ bu2,
    const float* __restrict__ n2_cs, const float* __restrict__ e2_cs, float* __restrict__ u2_out)
{
    const int j = threadIdx.x;
    float acc = bu2[j];
    for (int k = 0; k < H1; k++) acc += u1v[k] * Wu2[k*H2 + j];
    for (int k = 0; k < H2; k++) acc += (n2_cs[k] * (1.f/NN)) * Wgn2[k*H2 + j];
    for (int k = 0; k < H2; k++) acc += (e2_cs[k] * (1.f/NE)) * Wge2[k*H2 + j];
    u2_out[j] = fmaxf(acc, 0.f);
}

// ---------------- launcher ----------------
extern "C" void kernel_launch(void* const* d_in, const int* in_sizes, int n_in,
                              void* d_out, int out_size, void* d_ws, size_t ws_size,
                              hipStream_t stream)
{
    (void)in_sizes; (void)n_in; (void)out_size; (void)ws_size;
    const float* nodes = (const float*)d_in[0];
    const float* edges = (const float*)d_in[1];
    const float* gu    = (const float*)d_in[2];
    const int* senders   = (const int*)d_in[3];
    const int* receivers = (const int*)d_in[4];
    const float* We1  = (const float*)d_in[5];  const float* be1 = (const float*)d_in[6];
    const float* Wn1  = (const float*)d_in[7];  const float* Win1= (const float*)d_in[8];
    const float* Wout1= (const float*)d_in[9];  const float* bn1 = (const float*)d_in[10];
    const float* Wu1  = (const float*)d_in[11]; const float* Wgn1= (const float*)d_in[12];
    const float* Wge1 = (const float*)d_in[13]; const float* bu1 = (const float*)d_in[14];
    const float* We2  = (const float*)d_in[15]; const float* be2 = (const float*)d_in[16];
    const float* Wn2  = (const float*)d_in[17]; const float* Win2= (const float*)d_in[18];
    const float* Wout2= (const float*)d_in[19]; const float* bn2 = (const float*)d_in[20];
    const float* Wu2  = (const float*)d_in[21]; const float* Wgn2= (const float*)d_in[22];
    const float* Wge2 = (const float*)d_in[23]; const float* bu2 = (const float*)d_in[24];

    float* ws = (float*)d_ws;
    size_t o = 0;
    float* inc1   = ws + o;  o += (size_t)NN*H1;
    float* out1   = ws + o;  o += (size_t)NN*H1;
    float* inc2   = ws + o;  o += (size_t)NN*H2;
    float* out2   = ws + o;  o += (size_t)NN*H2;
    float* deg_in = ws + o;  o += 65536;
    float* deg_out= ws + o;  o += 65536;
    float* e1_cs  = ws + o;  o += 256;
    float* n1_cs  = ws + o;  o += 256;
    float* e2_cs  = ws + o;  o += 128;
    float* n2_cs  = ws + o;  o += 128;
    float* u1v    = ws + o;  o += 256;
    const size_t zero_bytes = o * sizeof(float);
    bf16* n1 = (bf16*)(ws + o);   // N*H1 bf16 = 25.6 MB

    float* n2_out = (float*)d_out;
    float* e2_out = n2_out + (size_t)NN*H2;
    float* u2_out = n2_out + (size_t)(NN + NE)*H2;

    hipMemsetAsync(d_ws, 0, zero_bytes, stream);

    edge_all<<<NE/EPB, 256, 0, stream>>>(edges, senders, receivers, We1, be1, We2, be2,
        inc1, out1, inc2, out2, deg_in, deg_out, e2_out);

    node1_kernel<<<(NN + 63)/64, 256, 0, stream>>>(nodes, inc1, out1, deg_in, deg_out,
        Wn1, Win1, Wout1, bn1, n1, n1_cs);

    colsum<<<128, 256, 0, stream>>>(inc1, NN, H1, e1_cs);
    colsum<<<128, 256, 0, stream>>>(inc2, NN, H2, e2_cs);

    u1_kernel<<<1, H1, 0, stream>>>(gu, Wu1, Wgn1, Wge1, bu1, n1_cs, e1_cs, u1v);

    node2_kernel<<<(NN + 63)/64, 256, 0, stream>>>(n1, inc2, out2, deg_in, deg_out,
        Wn2, Win2, Wout2, bn2, n2_out, n2_cs);

    u2_kernel<<<1, H2, 0, stream>>>(u1v, Wu2, Wgn2, Wge2, bu2, n2_cs, e2_cs, u2_out);
}

// Round 3
// 1721.053 us; speedup vs baseline: 1.5866x; 1.5866x over previous
//
#include <hip/hip_runtime.h>
#include <hip/hip_bf16.h>
#include <stdint.h>

#define NN 50000
#define NE 400000
#define FN 32
#define FE 16
#define FG 16
#define H1 256
#define H2 128

typedef unsigned short u16;
typedef __bf16 bfv8 __attribute__((ext_vector_type(8)));
typedef float f32v4 __attribute__((ext_vector_type(4)));
typedef u16 usv4 __attribute__((ext_vector_type(4)));
typedef u16 usv8 __attribute__((ext_vector_type(8)));

#define EPB 64    // edges per block in edge_all
#define APK 264   // LDS pitch (bf16 elems) per row: 528 B -> lane stride 16 mod 128 (2-way max)

__device__ __forceinline__ u16 f2b(float x){
  __hip_bfloat16 h = __float2bfloat16(x);
  return *reinterpret_cast<u16*>(&h);
}

// ---------------- MFMA GEMM over LDS A-tile [row][k] (pitch APK) and frag-packed B ----------------
// B packed as: elem[((ck*NNT + nt)*64 + lane)*8 + j] = bf16(B[ck*32 + (lane>>4)*8 + j][nt*16 + (lane&15)])
template<int NCK, int NNT>
__device__ __forceinline__ void gemm_tiles(const u16* a_s, const u16* __restrict__ pB,
                                           int w, int l, f32v4* acc)
{
  const int lr = l & 15, q = l >> 4;
  const bfv8* bp = (const bfv8*)pB;
  for (int ck = 0; ck < NCK; ck++){
    bfv8 a = *(const bfv8*)&a_s[(w*16 + lr)*APK + ck*32 + q*8];
    #pragma unroll
    for (int nt = 0; nt < NNT; nt++){
      bfv8 b = bp[(ck*NNT + nt)*64 + l];
      acc[nt] = __builtin_amdgcn_mfma_f32_16x16x32_bf16(a, b, acc[nt], 0, 0, 0);
    }
  }
}

// stage 64 rows x (4<<C4PR_LOG2) f32 cols from global into LDS bf16 [row][k], optional per-row scale
template<int C4PR_LOG2>
__device__ __forceinline__ void stage_rows(u16* a_s, const float* __restrict__ src,
                                           long n0, const float* rd, int t)
{
  const int c4pr = 1 << C4PR_LOG2;
  for (int idx = t; idx < 64*c4pr; idx += 256){
    int row = idx >> C4PR_LOG2, c4 = idx & (c4pr - 1);
    long n = n0 + row;
    float x0=0.f, x1=0.f, x2=0.f, x3=0.f;
    if (n < NN){
      const float4 v = *(const float4*)&src[(n << (C4PR_LOG2 + 2)) + c4*4];
      float s = rd ? rd[row] : 1.f;
      x0 = v.x*s; x1 = v.y*s; x2 = v.z*s; x3 = v.w*s;
    }
    usv4 o; o.x = f2b(x0); o.y = f2b(x1); o.z = f2b(x2); o.w = f2b(x3);
    *(usv4*)&a_s[row*APK + c4*4] = o;
  }
}

// ---------------- weight pre-pack into MFMA fragment order (bf16) ----------------
struct PD { const float* src; u16* dst; int K, N; };
struct PackArgs { PD d[7]; };

__global__ __launch_bounds__(64) void pack_weights(PackArgs A){
  int b = blockIdx.x, l = threadIdx.x;
  int mi = 0, base = 0;
  for (; mi < 7; mi++){
    int tiles = (A.d[mi].K >> 5) * (A.d[mi].N >> 4);
    if (b < base + tiles) break;
    base += tiles;
  }
  const PD d = A.d[mi];
  const int tile = b - base;
  const int ntn = d.N >> 4;
  const int ck = tile / ntn, nt = tile % ntn;
  const int lr = l & 15, q = l >> 4;
  const int col = nt*16 + lr;
  usv8 o;
  #pragma unroll
  for (int j = 0; j < 8; j++){
    int k = ck*32 + q*8 + j;
    o[j] = f2b(d.src[(long)k * d.N + col]);
  }
  *(usv8*)&d.dst[((long)tile*64 + l)*8] = o;
}

// ---------------- fused edge kernel: e1 (VALU) + scatter1 + e2 (MFMA) + scatter2 ----------------
__global__ __launch_bounds__(256) void edge_all(
    const float* __restrict__ edges, const int* __restrict__ senders, const int* __restrict__ receivers,
    const float* __restrict__ We1, const float* __restrict__ be1,
    const u16* __restrict__ pWe2, const float* __restrict__ be2,
    float* __restrict__ inc1, float* __restrict__ out1,
    float* __restrict__ inc2, float* __restrict__ out2,
    float* __restrict__ deg_in, float* __restrict__ deg_out,
    float* __restrict__ e2_out)
{
    __shared__ __align__(16) u16 e1s[EPB*APK];   // e1 tile [edge][k], 33.8 KB
    __shared__ __align__(16) float er[EPB*FE];   // staged edge rows
    __shared__ int rs[EPB], ss[EPB];
    const int t = threadIdx.x;
    const long e0 = (long)blockIdx.x * EPB;

    // stage 64 edge rows (4 KB) + indices, coalesced
    {
      const float4* src = (const float4*)(edges + e0*FE);
      float4 v = src[t];
      int b = t*4;
      er[b] = v.x; er[b+1] = v.y; er[b+2] = v.z; er[b+3] = v.w;
    }
    if (t < EPB)          rs[t]     = receivers[e0 + t];
    else if (t < 2*EPB)   ss[t-EPB] = senders[e0 + t - EPB];
    __syncthreads();

    if (t < EPB)        atomicAdd(&deg_in [rs[t]],     1.0f);
    else if (t < 2*EPB) atomicAdd(&deg_out[ss[t-EPB]], 1.0f);

    // e1: thread t owns column k=t across 64 edges; fused scatter into inc1/out1
    {
      float w[FE];
      #pragma unroll
      for (int c = 0; c < FE; c++) w[c] = We1[c*H1 + t];
      const float bk = be1[t];
      #pragma unroll 4
      for (int i = 0; i < EPB; i++){
        const float4* e4 = (const float4*)&er[i*FE];
        float4 a0 = e4[0], a1 = e4[1], a2 = e4[2], a3 = e4[3];
        float acc = bk;
        acc += a0.x*w[0] + a0.y*w[1] + a0.z*w[2] + a0.w*w[3];
        acc += a1.x*w[4] + a1.y*w[5] + a1.z*w[6] + a1.w*w[7];
        acc += a2.x*w[8] + a2.y*w[9] + a2.z*w[10]+ a2.w*w[11];
        acc += a3.x*w[12]+ a3.y*w[13]+ a3.z*w[14]+ a3.w*w[15];
        float v = fmaxf(acc, 0.f);
        e1s[i*APK + t] = f2b(v);
        atomicAdd(&inc1[(long)rs[i]*H1 + t], v);
        atomicAdd(&out1[(long)ss[i]*H1 + t], v);
      }
    }
    __syncthreads();

    // e2 = relu(e1 @ We2 + be2) via MFMA: wave w owns m-tile w (16 edges) x 8 n-tiles
    const int w = t >> 6, l = t & 63;
    const int lr = l & 15, q = l >> 4;
    f32v4 acc[8];
    #pragma unroll
    for (int nt = 0; nt < 8; nt++) acc[nt] = (f32v4){0.f,0.f,0.f,0.f};

    gemm_tiles<8,8>(e1s, pWe2, w, l, acc);

    #pragma unroll
    for (int nt = 0; nt < 8; nt++){
      const int j = nt*16 + lr;
      const float b = be2[j];
      #pragma unroll
      for (int r = 0; r < 4; r++){
        const int m = w*16 + q*4 + r;
        float v = fmaxf(acc[nt][r] + b, 0.f);
        e2_out[(e0 + m)*H2 + j] = v;
        atomicAdd(&inc2[(long)rs[m]*H2 + j], v);
        atomicAdd(&out2[(long)ss[m]*H2 + j], v);
      }
    }
}

// ---------------- fused node kernel: n1 (kept in LDS) -> n2, both MFMA ----------------
__global__ __launch_bounds__(256) void node_fused(
    const float* __restrict__ nodes,
    const float* __restrict__ inc1, const float* __restrict__ out1,
    const float* __restrict__ inc2, const float* __restrict__ out2,
    const float* __restrict__ deg_in, const float* __restrict__ deg_out,
    const u16* __restrict__ pWn1, const u16* __restrict__ pWin1, const u16* __restrict__ pWout1,
    const float* __restrict__ bn1,
    const u16* __restrict__ pWn2, const u16* __restrict__ pWin2, const u16* __restrict__ pWout2,
    const float* __restrict__ bn2,
    float* __restrict__ n1_cs, float* __restrict__ n2_cs,
    float* __restrict__ n2_out)
{
    __shared__ __align__(16) u16 a_s[64*APK];    // 33.8 KB, reused across phases
    __shared__ float rdin[64], rdout[64], cs_s[H1];
    const int t = threadIdx.x;
    const long n0 = (long)blockIdx.x * 64;
    const int w = t >> 6, l = t & 63;
    const int lr = l & 15, q = l >> 4;

    cs_s[t] = 0.f;
    if (t < 64){ long n = n0 + t;      rdin [t]    = (n < NN) ? 1.f/fmaxf(deg_in [n], 1.f) : 0.f; }
    else if (t < 128){ long n = n0+t-64; rdout[t-64] = (n < NN) ? 1.f/fmaxf(deg_out[n], 1.f) : 0.f; }
    __syncthreads();

    // ---- block 1: n1 = relu(nodes@Wn1 + (inc1/deg)@Win1 + (out1/deg)@Wout1 + bn1)
    f32v4 acc1[16];
    #pragma unroll
    for (int nt = 0; nt < 16; nt++) acc1[nt] = (f32v4){0.f,0.f,0.f,0.f};

    stage_rows<6>(a_s, inc1, n0, rdin, t);
    __syncthreads();
    gemm_tiles<8,16>(a_s, pWin1, w, l, acc1);
    __syncthreads();

    stage_rows<6>(a_s, out1, n0, rdout, t);
    __syncthreads();
    gemm_tiles<8,16>(a_s, pWout1, w, l, acc1);
    __syncthreads();

    stage_rows<3>(a_s, nodes, n0, nullptr, t);
    __syncthreads();
    gemm_tiles<1,16>(a_s, pWn1, w, l, acc1);
    __syncthreads();   // done reading a_s; safe to overwrite with n1

    // epilogue: n1 tile -> LDS (A-layout for block 2) + column-sum reduction
    #pragma unroll
    for (int nt = 0; nt < 16; nt++){
      const int j = nt*16 + lr;
      const float b = bn1[j];
      float part = 0.f;
      #pragma unroll
      for (int r = 0; r < 4; r++){
        const int row = w*16 + q*4 + r;
        float v = 0.f;
        if (n0 + row < NN){ v = fmaxf(acc1[nt][r] + b, 0.f); part += v; }
        a_s[row*APK + j] = f2b(v);
      }
      atomicAdd(&cs_s[j], part);
    }
    __syncthreads();
    atomicAdd(&n1_cs[t], cs_s[t]);
    if (t < H2) cs_s[t] = 0.f;       // re-zero for n2 colsum (barriers below order this)
    __syncthreads();

    // ---- block 2: n2 = relu(n1@Wn2 + (inc2/deg)@Win2 + (out2/deg)@Wout2 + bn2)
    f32v4 acc2[8];
    #pragma unroll
    for (int nt = 0; nt < 8; nt++) acc2[nt] = (f32v4){0.f,0.f,0.f,0.f};

    gemm_tiles<8,8>(a_s, pWn2, w, l, acc2);   // A = n1 (already in LDS)
    __syncthreads();

    stage_rows<5>(a_s, inc2, n0, rdin, t);
    __syncthreads();
    gemm_tiles<4,8>(a_s, pWin2, w, l, acc2);
    __syncthreads();

    stage_rows<5>(a_s, out2, n0, rdout, t);
    __syncthreads();
    gemm_tiles<4,8>(a_s, pWout2, w, l, acc2);

    #pragma unroll
    for (int nt = 0; nt < 8; nt++){
      const int j = nt*16 + lr;
      const float b = bn2[j];
      float part = 0.f;
      #pragma unroll
      for (int r = 0; r < 4; r++){
        const int row = w*16 + q*4 + r;
        const long n = n0 + row;
        if (n < NN){
          float v = fmaxf(acc2[nt][r] + b, 0.f);
          n2_out[n*H2 + j] = v;
          part += v;
        }
      }
      atomicAdd(&cs_s[j], part);
    }
    __syncthreads();
    if (t < H2) atomicAdd(&n2_cs[t], cs_s[t]);
}

// ---------------- column-sum over [rows, W] f32 -> dst[W] ----------------
__global__ __launch_bounds__(256) void colsum(const float* __restrict__ src, int rows, int W,
                                              float* __restrict__ dst)
{
    const int t = threadIdx.x;
    const int j = t % W;
    const int rsub = t / W;
    const int rpb = 256 / W;
    float s = 0.f;
    for (long r = (long)blockIdx.x * rpb + rsub; r < rows; r += (long)gridDim.x * rpb)
      s += src[r*W + j];
    atomicAdd(&dst[j], s);
}

// ---------------- global updates ----------------
__global__ void u1_kernel(const float* __restrict__ gu, const float* __restrict__ Wu1,
    const float* __restrict__ Wgn1, const float* __restrict__ Wge1, const float* __restrict__ bu1,
    const float* __restrict__ n1_cs, const float* __restrict__ e1_cs, float* __restrict__ u1v)
{
    const int j = threadIdx.x;
    float acc = bu1[j];
    #pragma unroll
    for (int k = 0; k < FG; k++) acc += gu[k] * Wu1[k*H1 + j];
    for (int k = 0; k < H1; k++) acc += (n1_cs[k] * (1.f/NN)) * Wgn1[k*H1 + j];
    for (int k = 0; k < H1; k++) acc += (e1_cs[k] * (1.f/NE)) * Wge1[k*H1 + j];
    u1v[j] = fmaxf(acc, 0.f);
}

__global__ void u2_kernel(const float* __restrict__ u1v, const float* __restrict__ Wu2,
    const float* __restrict__ Wgn2, const float* __restrict__ Wge2, const float* __restrict__ bu2,
    const float* __restrict__ n2_cs, const float* __restrict__ e2_cs, float* __restrict__ u2_out)
{
    const int j = threadIdx.x;
    float acc = bu2[j];
    for (int k = 0; k < H1; k++) acc += u1v[k] * Wu2[k*H2 + j];
    for (int k = 0; k < H2; k++) acc += (n2_cs[k] * (1.f/NN)) * Wgn2[k*H2 + j];
    for (int k = 0; k < H2; k++) acc += (e2_cs[k] * (1.f/NE)) * Wge2[k*H2 + j];
    u2_out[j] = fmaxf(acc, 0.f);
}

// ---------------- launcher ----------------
extern "C" void kernel_launch(void* const* d_in, const int* in_sizes, int n_in,
                              void* d_out, int out_size, void* d_ws, size_t ws_size,
                              hipStream_t stream)
{
    (void)in_sizes; (void)n_in; (void)out_size; (void)ws_size;
    const float* nodes = (const float*)d_in[0];
    const float* edges = (const float*)d_in[1];
    const float* gu    = (const float*)d_in[2];
    const int* senders   = (const int*)d_in[3];
    const int* receivers = (const int*)d_in[4];
    const float* We1  = (const float*)d_in[5];  const float* be1 = (const float*)d_in[6];
    const float* Wn1  = (const float*)d_in[7];  const float* Win1= (const float*)d_in[8];
    const float* Wout1= (const float*)d_in[9];  const float* bn1 = (const float*)d_in[10];
    const float* Wu1  = (const float*)d_in[11]; const float* Wgn1= (const float*)d_in[12];
    const float* Wge1 = (const float*)d_in[13]; const float* bu1 = (const float*)d_in[14];
    const float* We2  = (const float*)d_in[15]; const float* be2 = (const float*)d_in[16];
    const float* Wn2  = (const float*)d_in[17]; const float* Win2= (const float*)d_in[18];
    const float* Wout2= (const float*)d_in[19]; const float* bn2 = (const float*)d_in[20];
    const float* Wu2  = (const float*)d_in[21]; const float* Wgn2= (const float*)d_in[22];
    const float* Wge2 = (const float*)d_in[23]; const float* bu2 = (const float*)d_in[24];

    float* ws = (float*)d_ws;
    size_t o = 0;
    float* inc1   = ws + o;  o += (size_t)NN*H1;
    float* out1   = ws + o;  o += (size_t)NN*H1;
    float* inc2   = ws + o;  o += (size_t)NN*H2;
    float* out2   = ws + o;  o += (size_t)NN*H2;
    float* deg_in = ws + o;  o += 65536;
    float* deg_out= ws + o;  o += 65536;
    float* e1_cs  = ws + o;  o += 256;
    float* n1_cs  = ws + o;  o += 256;
    float* e2_cs  = ws + o;  o += 128;
    float* n2_cs  = ws + o;  o += 128;
    float* u1v    = ws + o;  o += 256;
    const size_t zero_bytes = o * sizeof(float);

    // packed bf16 weights (fragment order), 16B-aligned
    u16* pbase = (u16*)(ws + o);
    size_t po = 0;
    u16* pWin1 = pbase + po;  po += (size_t)H1*H1;   // 256x256
    u16* pWout1= pbase + po;  po += (size_t)H1*H1;
    u16* pWn1  = pbase + po;  po += (size_t)FN*H1;   // 32x256
    u16* pWe2  = pbase + po;  po += (size_t)H1*H2;   // 256x128
    u16* pWn2  = pbase + po;  po += (size_t)H1*H2;
    u16* pWin2 = pbase + po;  po += (size_t)H2*H2;   // 128x128
    u16* pWout2= pbase + po;  po += (size_t)H2*H2;

    float* n2_out = (float*)d_out;
    float* e2_out = n2_out + (size_t)NN*H2;
    float* u2_out = n2_out + (size_t)(NN + NE)*H2;

    hipMemsetAsync(d_ws, 0, zero_bytes, stream);

    PackArgs pa;
    pa.d[0] = {Win1,  pWin1,  H1, H1};
    pa.d[1] = {Wout1, pWout1, H1, H1};
    pa.d[2] = {Wn1,   pWn1,   FN, H1};
    pa.d[3] = {We2,   pWe2,   H1, H2};
    pa.d[4] = {Wn2,   pWn2,   H1, H2};
    pa.d[5] = {Win2,  pWin2,  H2, H2};
    pa.d[6] = {Wout2, pWout2, H2, H2};
    int total_tiles = 0;
    for (int i = 0; i < 7; i++) total_tiles += (pa.d[i].K >> 5) * (pa.d[i].N >> 4);
    pack_weights<<<total_tiles, 64, 0, stream>>>(pa);

    edge_all<<<NE/EPB, 256, 0, stream>>>(edges, senders, receivers, We1, be1, pWe2, be2,
        inc1, out1, inc2, out2, deg_in, deg_out, e2_out);

    colsum<<<128, 256, 0, stream>>>(inc1, NN, H1, e1_cs);

    node_fused<<<(NN + 63)/64, 256, 0, stream>>>(nodes, inc1, out1, inc2, out2,
        deg_in, deg_out, pWn1, pWin1, pWout1, bn1, pWn2, pWin2, pWout2, bn2,
        n1_cs, n2_cs, n2_out);

    colsum<<<128, 256, 0, stream>>>(inc2, NN, H2, e2_cs);

    u1_kernel<<<1, H1, 0, stream>>>(gu, Wu1, Wgn1, Wge1, bu1, n1_cs, e1_cs, u1v);

    u2_kernel<<<1, H2, 0, stream>>>(u1v, Wu2, Wgn2, Wge2, bu2, n2_cs, e2_cs, u2_out);
}

// Round 4
// 1248.446 us; speedup vs baseline: 2.1873x; 1.3786x over previous
//
#include <hip/hip_runtime.h>
#include <hip/hip_bf16.h>
#include <stdint.h>

#define NN 50000
#define NE 400000
#define FN 32
#define FE 16
#define FG 16
#define H1 256
#define H2 128
#define M2 (2*NN)          // concatenated [in-counts, out-counts]
#define SCAN_B 391         // ceil(M2/256)
#define LCAP 1536          // staged edge-list capacity per tile per direction

typedef unsigned short u16;
typedef __bf16 bfv8 __attribute__((ext_vector_type(8)));
typedef float f32v4 __attribute__((ext_vector_type(4)));
typedef u16 usv2 __attribute__((ext_vector_type(2)));
typedef u16 usv4 __attribute__((ext_vector_type(4)));
typedef u16 usv8 __attribute__((ext_vector_type(8)));

#define APK 264   // LDS pitch (bf16 elems): 528B rows
#define EP1 40    // LDS pitch for edge1's 64x32 tile (80B rows, 16B-aligned frag reads)

__device__ __forceinline__ u16 f2b(float x){
  __hip_bfloat16 h = __float2bfloat16(x);
  return *reinterpret_cast<u16*>(&h);
}
__device__ __forceinline__ float bf2f(u16 u){
  union{uint32_t i; float f;} v; v.i = ((uint32_t)u) << 16; return v.f;
}

// ---------------- MFMA GEMM over LDS A-tile [row][k] and frag-packed B ----------------
// B packed: dst[((ck*NNT+nt)*64 + lane)*8 + j] = bf16(B[ck*32 + (lane>>4)*8 + j][nt*16 + (lane&15)])
template<int NCK, int NNT, int PITCH>
__device__ __forceinline__ void gemm_tiles(const u16* a_s, const u16* __restrict__ pB,
                                           int w, int l, f32v4* acc)
{
  const int lr = l & 15, q = l >> 4;
  const bfv8* bp = (const bfv8*)pB;
  for (int ck = 0; ck < NCK; ck++){
    bfv8 a = *(const bfv8*)&a_s[(w*16 + lr)*PITCH + ck*32 + q*8];
    #pragma unroll
    for (int nt = 0; nt < NNT; nt++){
      bfv8 b = bp[(ck*NNT + nt)*64 + l];
      acc[nt] = __builtin_amdgcn_mfma_f32_16x16x32_bf16(a, b, acc[nt], 0, 0, 0);
    }
  }
}

// stage 64 rows x (4<<C4PR_LOG2) f32 cols from global into LDS bf16 [row][k] (pitch APK)
template<int C4PR_LOG2>
__device__ __forceinline__ void stage_rows(u16* a_s, const float* __restrict__ src,
                                           long n0, int t)
{
  const int c4pr = 1 << C4PR_LOG2;
  for (int idx = t; idx < 64*c4pr; idx += 256){
    int row = idx >> C4PR_LOG2, c4 = idx & (c4pr - 1);
    long n = n0 + row;
    float x0=0.f, x1=0.f, x2=0.f, x3=0.f;
    if (n < NN){
      const float4 v = *(const float4*)&src[(n << (C4PR_LOG2 + 2)) + c4*4];
      x0 = v.x; x1 = v.y; x2 = v.z; x3 = v.w;
    }
    usv4 o; o.x = f2b(x0); o.y = f2b(x1); o.z = f2b(x2); o.w = f2b(x3);
    *(usv4*)&a_s[row*APK + c4*4] = o;
  }
}

// ---------------- weight pre-pack into MFMA fragment order (bf16, K zero-padded to Ks<K) ---------
struct PD { const float* src; u16* dst; int K, N, Ks; };
struct PackArgs { PD d[8]; };

__global__ __launch_bounds__(64) void pack_weights(PackArgs A){
  int b = blockIdx.x, l = threadIdx.x;
  int mi = 0, base = 0;
  for (; mi < 8; mi++){
    int tiles = (A.d[mi].K >> 5) * (A.d[mi].N >> 4);
    if (b < base + tiles) break;
    base += tiles;
  }
  const PD d = A.d[mi];
  const int tile = b - base;
  const int ntn = d.N >> 4;
  const int ck = tile / ntn, nt = tile % ntn;
  const int lr = l & 15, q = l >> 4;
  const int col = nt*16 + lr;
  usv8 o;
  #pragma unroll
  for (int j = 0; j < 8; j++){
    int k = ck*32 + q*8 + j;
    o[j] = (k < d.Ks) ? f2b(d.src[(long)k * d.N + col]) : (u16)0;
  }
  *(usv8*)&d.dst[((long)tile*64 + l)*8] = o;
}

// ---------------- CSR build ----------------
__global__ __launch_bounds__(256) void csr_count(const int* __restrict__ recv,
    const int* __restrict__ send, int* cnt, int* pos_in, int* pos_out)
{
  int e = blockIdx.x*256 + threadIdx.x;
  if (e >= NE) return;
  pos_in [e] = atomicAdd(&cnt[recv[e]], 1);
  pos_out[e] = atomicAdd(&cnt[NN + send[e]], 1);
}

__global__ __launch_bounds__(256) void scan_blocks(const int* __restrict__ cnt,
    int* off, int* btot)
{
  __shared__ int s[256];
  int b = blockIdx.x, t = threadIdx.x;
  int i = b*256 + t;
  int v = (i < M2) ? cnt[i] : 0;
  s[t] = v; __syncthreads();
  int acc = v;
  for (int d = 1; d < 256; d <<= 1){
    int add = (t >= d) ? s[t-d] : 0;
    __syncthreads();
    acc += add; s[t] = acc;
    __syncthreads();
  }
  if (i < M2) off[i] = acc - v;     // block-local exclusive
  if (t == 255) btot[b] = acc;
}

__global__ __launch_bounds__(256) void scan_tops(int* btot){
  __shared__ int s[512], ts[256];
  int t = threadIdx.x;
  s[t]     = (t < SCAN_B) ? btot[t] : 0;
  s[256+t] = (256+t < SCAN_B) ? btot[256+t] : 0;
  __syncthreads();
  int a0 = s[2*t], a1 = s[2*t+1];
  int tot = a0 + a1;
  ts[t] = tot; __syncthreads();
  int acc = tot;
  for (int d = 1; d < 256; d <<= 1){
    int add = (t >= d) ? ts[t-d] : 0;
    __syncthreads();
    acc += add; ts[t] = acc;
    __syncthreads();
  }
  int excl = acc - tot;
  if (2*t   < SCAN_B) btot[2*t]   = excl;
  if (2*t+1 < SCAN_B) btot[2*t+1] = excl + a0;
}

__global__ __launch_bounds__(256) void scan_fix(int* off, const int* __restrict__ btot){
  int i = blockIdx.x*256 + threadIdx.x;
  if (i < M2) off[i] += btot[blockIdx.x];
}

__global__ __launch_bounds__(256) void csr_fill(const int* __restrict__ recv,
    const int* __restrict__ send, const int* __restrict__ off,
    const int* __restrict__ pos_in, const int* __restrict__ pos_out, int* lis)
{
  int e = blockIdx.x*256 + threadIdx.x;
  if (e >= NE) return;
  lis[off[recv[e]]      + pos_in [e]] = e;
  lis[off[NN + send[e]] + pos_out[e]] = e;
}

// ---------------- edge block 1: e1 = relu(edges@We1+be1) via MFMA, rows -> e1b (bf16) ------------
__global__ __launch_bounds__(256) void edge1_kernel(const float* __restrict__ edges,
    const u16* __restrict__ pWe1, const float* __restrict__ be1,
    u16* __restrict__ e1b, float* __restrict__ e1_cs)
{
  __shared__ __align__(16) u16 a_es[64*EP1];
  __shared__ float cs_s[H1];
  const int t = threadIdx.x;
  const long e0 = (long)blockIdx.x * 64;
  const int w = t >> 6, l = t & 63, lr = l & 15, q = l >> 4;
  cs_s[t] = 0.f;
  {
    int row = t >> 2, c4 = t & 3;
    float4 v = *(const float4*)&edges[(e0 + row)*FE + c4*4];
    usv4 o = { f2b(v.x), f2b(v.y), f2b(v.z), f2b(v.w) };
    *(usv4*)&a_es[row*EP1 + c4*4] = o;
    *(usv4*)&a_es[row*EP1 + 16 + c4*4] = (usv4){0,0,0,0};   // zero-pad k=16..31
  }
  __syncthreads();
  f32v4 acc[16];
  #pragma unroll
  for (int nt = 0; nt < 16; nt++) acc[nt] = (f32v4){0.f,0.f,0.f,0.f};
  gemm_tiles<1,16,EP1>(a_es, pWe1, w, l, acc);

  #pragma unroll
  for (int nt = 0; nt < 16; nt++){
    const int j = nt*16 + lr;
    const float b = be1[j];
    float part = 0.f;
    #pragma unroll
    for (int r = 0; r < 4; r++){
      const int m = w*16 + q*4 + r;
      float v = fmaxf(acc[nt][r] + b, 0.f);
      e1b[(e0 + m)*H1 + j] = f2b(v);
      part += v;
    }
    atomicAdd(&cs_s[j], part);
  }
  __syncthreads();
  atomicAdd(&e1_cs[t], cs_s[t]);
}

// ---------------- edge block 2: in-place e1b (bf16 rows) -> e2 (f32 rows) -----------------------
__global__ __launch_bounds__(256) void e2_kernel(float* __restrict__ e2f,
    const u16* __restrict__ pWe2, const float* __restrict__ be2, float* __restrict__ e2_cs)
{
  __shared__ __align__(16) u16 a_s[64*APK];
  __shared__ float cs_s[H2];
  const int t = threadIdx.x;
  const long e0 = (long)blockIdx.x * 64;
  const int w = t >> 6, l = t & 63, lr = l & 15, q = l >> 4;
  if (t < H2) cs_s[t] = 0.f;
  const u16* e1u = (const u16*)e2f;
  for (int idx = t; idx < 64*32; idx += 256){
    int row = idx >> 5, ch = idx & 31;
    usv8 v = *(const usv8*)&e1u[(e0 + row)*H1 + ch*8];
    *(usv8*)&a_s[row*APK + ch*8] = v;
  }
  __syncthreads();   // all reads of this block's rows complete before overwrite below
  f32v4 acc[8];
  #pragma unroll
  for (int nt = 0; nt < 8; nt++) acc[nt] = (f32v4){0.f,0.f,0.f,0.f};
  gemm_tiles<8,8,APK>(a_s, pWe2, w, l, acc);

  #pragma unroll
  for (int nt = 0; nt < 8; nt++){
    const int j = nt*16 + lr;
    const float b = be2[j];
    float part = 0.f;
    #pragma unroll
    for (int r = 0; r < 4; r++){
      const int m = w*16 + q*4 + r;
      float v = fmaxf(acc[nt][r] + b, 0.f);
      e2f[(e0 + m)*H2 + j] = v;
      part += v;
    }
    atomicAdd(&cs_s[j], part);
  }
  __syncthreads();
  if (t < H2) atomicAdd(&e2_cs[t], cs_s[t]);
}

// ---------------- gathers: mean of rows listed in CSR -> LDS A-tile ----------------
__device__ __forceinline__ void gather_h1(u16* a_s, const u16* __restrict__ src,
    const int* lst, const int* roff, int base, const int* __restrict__ lis_g, int w, int l)
{
  for (int rr = 0; rr < 16; rr++){
    int r = w + rr*4;
    int rs = roff[r] - base, re = roff[r+1] - base;
    float s0=0.f, s1=0.f, s2=0.f, s3=0.f;
    int j = rs;
    for (; j + 2 <= re; j += 2){
      int eA = (j   < LCAP) ? lst[j]   : lis_g[base + j];
      int eB = (j+1 < LCAP) ? lst[j+1] : lis_g[base + j + 1];
      usv4 a = *(const usv4*)&src[(long)eA*H1 + l*4];
      usv4 b = *(const usv4*)&src[(long)eB*H1 + l*4];
      s0 += bf2f(a.x) + bf2f(b.x); s1 += bf2f(a.y) + bf2f(b.y);
      s2 += bf2f(a.z) + bf2f(b.z); s3 += bf2f(a.w) + bf2f(b.w);
    }
    if (j < re){
      int eA = (j < LCAP) ? lst[j] : lis_g[base + j];
      usv4 a = *(const usv4*)&src[(long)eA*H1 + l*4];
      s0 += bf2f(a.x); s1 += bf2f(a.y); s2 += bf2f(a.z); s3 += bf2f(a.w);
    }
    float rd = 1.f / fmaxf((float)(re - rs), 1.f);
    usv4 o = { f2b(s0*rd), f2b(s1*rd), f2b(s2*rd), f2b(s3*rd) };
    *(usv4*)&a_s[r*APK + l*4] = o;
  }
}

__device__ __forceinline__ void gather_h2(u16* a_s, const float* __restrict__ src,
    const int* lst, const int* roff, int base, const int* __restrict__ lis_g, int w, int l)
{
  for (int rr = 0; rr < 16; rr++){
    int r = w + rr*4;
    int rs = roff[r] - base, re = roff[r+1] - base;
    float s0=0.f, s1=0.f;
    int j = rs;
    for (; j + 2 <= re; j += 2){
      int eA = (j   < LCAP) ? lst[j]   : lis_g[base + j];
      int eB = (j+1 < LCAP) ? lst[j+1] : lis_g[base + j + 1];
      float2 a = *(const float2*)&src[(long)eA*H2 + l*2];
      float2 b = *(const float2*)&src[(long)eB*H2 + l*2];
      s0 += a.x + b.x; s1 += a.y + b.y;
    }
    if (j < re){
      int eA = (j < LCAP) ? lst[j] : lis_g[base + j];
      float2 a = *(const float2*)&src[(long)eA*H2 + l*2];
      s0 += a.x; s1 += a.y;
    }
    float rd = 1.f / fmaxf((float)(re - rs), 1.f);
    usv2 o = { f2b(s0*rd), f2b(s1*rd) };
    *(usv2*)&a_s[r*APK + l*2] = o;
  }
}

// ---------------- node block 1 ----------------
__global__ __launch_bounds__(256) void node1_kernel(
    const float* __restrict__ nodes, const u16* __restrict__ e1b,
    const int* __restrict__ off, const int* __restrict__ lis,
    const u16* __restrict__ pWn1, const u16* __restrict__ pWin1, const u16* __restrict__ pWout1,
    const float* __restrict__ bn1, u16* __restrict__ n1b, float* __restrict__ n1_cs)
{
  __shared__ __align__(16) u16 a_s[64*APK];
  __shared__ int ilA[LCAP], ilB[LCAP];
  __shared__ int roff[65], roff2[65];
  __shared__ float cs_s[H1];
  const int t = threadIdx.x;
  const long n0 = (long)blockIdx.x * 64;
  const int w = t >> 6, l = t & 63, lr = l & 15, q = l >> 4;

  cs_s[t] = 0.f;
  if (t <= 64){
    long idx = n0 + t;
    roff [t] = (idx >= NN) ? NE     : off[idx];
    roff2[t] = (idx >= NN) ? 2*NE   : off[NN + idx];
  }
  __syncthreads();
  const int inb = roff[0],  in_total  = roff[64]  - inb;
  const int onb = roff2[0], out_total = roff2[64] - onb;
  for (int j = t; j < in_total  && j < LCAP; j += 256) ilA[j] = lis[inb + j];
  for (int j = t; j < out_total && j < LCAP; j += 256) ilB[j] = lis[onb + j];
  __syncthreads();

  f32v4 acc[16];
  #pragma unroll
  for (int nt = 0; nt < 16; nt++) acc[nt] = (f32v4){0.f,0.f,0.f,0.f};

  gather_h1(a_s, e1b, ilA, roff, inb, lis, w, l);
  __syncthreads();
  gemm_tiles<8,16,APK>(a_s, pWin1, w, l, acc);
  __syncthreads();

  gather_h1(a_s, e1b, ilB, roff2, onb, lis, w, l);
  __syncthreads();
  gemm_tiles<8,16,APK>(a_s, pWout1, w, l, acc);
  __syncthreads();

  stage_rows<3>(a_s, nodes, n0, t);
  __syncthreads();
  gemm_tiles<1,16,APK>(a_s, pWn1, w, l, acc);

  #pragma unroll
  for (int nt = 0; nt < 16; nt++){
    const int j = nt*16 + lr;
    const float b = bn1[j];
    float part = 0.f;
    #pragma unroll
    for (int r = 0; r < 4; r++){
      const int row = w*16 + q*4 + r;
      const long n = n0 + row;
      if (n < NN){
        float v = fmaxf(acc[nt][r] + b, 0.f);
        n1b[n*H1 + j] = f2b(v);
        part += v;
      }
    }
    atomicAdd(&cs_s[j], part);
  }
  __syncthreads();
  atomicAdd(&n1_cs[t], cs_s[t]);
}

// ---------------- node block 2 ----------------
__global__ __launch_bounds__(256) void node2_kernel(
    const u16* __restrict__ n1b, const float* __restrict__ e2f,
    const int* __restrict__ off, const int* __restrict__ lis,
    const u16* __restrict__ pWn2, const u16* __restrict__ pWin2, const u16* __restrict__ pWout2,
    const float* __restrict__ bn2, float* __restrict__ n2_out, float* __restrict__ n2_cs)
{
  __shared__ __align__(16) u16 a_s[64*APK];
  __shared__ int ilA[LCAP], ilB[LCAP];
  __shared__ int roff[65], roff2[65];
  __shared__ float cs_s[H2];
  const int t = threadIdx.x;
  const long n0 = (long)blockIdx.x * 64;
  const int w = t >> 6, l = t & 63, lr = l & 15, q = l >> 4;

  if (t < H2) cs_s[t] = 0.f;
  if (t <= 64){
    long idx = n0 + t;
    roff [t] = (idx >= NN) ? NE     : off[idx];
    roff2[t] = (idx >= NN) ? 2*NE   : off[NN + idx];
  }
  __syncthreads();
  const int inb = roff[0],  in_total  = roff[64]  - inb;
  const int onb = roff2[0], out_total = roff2[64] - onb;
  for (int j = t; j < in_total  && j < LCAP; j += 256) ilA[j] = lis[inb + j];
  for (int j = t; j < out_total && j < LCAP; j += 256) ilB[j] = lis[onb + j];
  __syncthreads();

  f32v4 acc[8];
  #pragma unroll
  for (int nt = 0; nt < 8; nt++) acc[nt] = (f32v4){0.f,0.f,0.f,0.f};

  // A = n1 (bf16 rows in ws)
  for (int idx = t; idx < 64*32; idx += 256){
    int row = idx >> 5, ch = idx & 31;
    long n = n0 + row;
    usv8 v = (usv8){0,0,0,0,0,0,0,0};
    if (n < NN) v = *(const usv8*)&n1b[n*H1 + ch*8];
    *(usv8*)&a_s[row*APK + ch*8] = v;
  }
  __syncthreads();
  gemm_tiles<8,8,APK>(a_s, pWn2, w, l, acc);
  __syncthreads();

  gather_h2(a_s, e2f, ilA, roff, inb, lis, w, l);
  __syncthreads();
  gemm_tiles<4,8,APK>(a_s, pWin2, w, l, acc);
  __syncthreads();

  gather_h2(a_s, e2f, ilB, roff2, onb, lis, w, l);
  __syncthreads();
  gemm_tiles<4,8,APK>(a_s, pWout2, w, l, acc);

  #pragma unroll
  for (int nt = 0; nt < 8; nt++){
    const int j = nt*16 + lr;
    const float b = bn2[j];
    float part = 0.f;
    #pragma unroll
    for (int r = 0; r < 4; r++){
      const int row = w*16 + q*4 + r;
      const long n = n0 + row;
      if (n < NN){
        float v = fmaxf(acc[nt][r] + b, 0.f);
        n2_out[n*H2 + j] = v;
        part += v;
      }
    }
    atomicAdd(&cs_s[j], part);
  }
  __syncthreads();
  if (t < H2) atomicAdd(&n2_cs[t], cs_s[t]);
}

// ---------------- global updates ----------------
__global__ void u1_kernel(const float* __restrict__ gu, const float* __restrict__ Wu1,
    const float* __restrict__ Wgn1, const float* __restrict__ Wge1, const float* __restrict__ bu1,
    const float* __restrict__ n1_cs, const float* __restrict__ e1_cs, float* __restrict__ u1v)
{
    const int j = threadIdx.x;
    float acc = bu1[j];
    #pragma unroll
    for (int k = 0; k < FG; k++) acc += gu[k] * Wu1[k*H1 + j];
    for (int k = 0; k < H1; k++) acc += (n1_cs[k] * (1.f/NN)) * Wgn1[k*H1 + j];
    for (int k = 0; k < H1; k++) acc += (e1_cs[k] * (1.f/NE)) * Wge1[k*H1 + j];
    u1v[j] = fmaxf(acc, 0.f);
}

__global__ void u2_kernel(const float* __restrict__ u1v, const float* __restrict__ Wu2,
    const float* __restrict__ Wgn2, const float* __restrict__ Wge2, const float* __restrict__ bu2,
    const float* __restrict__ n2_cs, const float* __restrict__ e2_cs, float* __restrict__ u2_out)
{
    const int j = threadIdx.x;
    float acc = bu2[j];
    for (int k = 0; k < H1; k++) acc += u1v[k] * Wu2[k*H2 + j];
    for (int k = 0; k < H2; k++) acc += (n2_cs[k] * (1.f/NN)) * Wgn2[k*H2 + j];
    for (int k = 0; k < H2; k++) acc += (e2_cs[k] * (1.f/NE)) * Wge2[k*H2 + j];
    u2_out[j] = fmaxf(acc, 0.f);
}

// ---------------- launcher ----------------
extern "C" void kernel_launch(void* const* d_in, const int* in_sizes, int n_in,
                              void* d_out, int out_size, void* d_ws, size_t ws_size,
                              hipStream_t stream)
{
    (void)in_sizes; (void)n_in; (void)out_size; (void)ws_size;
    const float* nodes = (const float*)d_in[0];
    const float* edges = (const float*)d_in[1];
    const float* gu    = (const float*)d_in[2];
    const int* senders   = (const int*)d_in[3];
    const int* receivers = (const int*)d_in[4];
    const float* We1  = (const float*)d_in[5];  const float* be1 = (const float*)d_in[6];
    const float* Wn1  = (const float*)d_in[7];  const float* Win1= (const float*)d_in[8];
    const float* Wout1= (const float*)d_in[9];  const float* bn1 = (const float*)d_in[10];
    const float* Wu1  = (const float*)d_in[11]; const float* Wgn1= (const float*)d_in[12];
    const float* Wge1 = (const float*)d_in[13]; const float* bu1 = (const float*)d_in[14];
    const float* We2  = (const float*)d_in[15]; const float* be2 = (const float*)d_in[16];
    const float* Wn2  = (const float*)d_in[17]; const float* Win2= (const float*)d_in[18];
    const float* Wout2= (const float*)d_in[19]; const float* bn2 = (const float*)d_in[20];
    const float* Wu2  = (const float*)d_in[21]; const float* Wgn2= (const float*)d_in[22];
    const float* Wge2 = (const float*)d_in[23]; const float* bu2 = (const float*)d_in[24];

    float* ws = (float*)d_ws;
    size_t o = 0;
    int*   cnt    = (int*)(ws + o);  o += M2;        // zeroed
    float* e1_cs  = ws + o;          o += 256;       // zeroed
    float* n1_cs  = ws + o;          o += 256;       // zeroed
    float* e2_cs  = ws + o;          o += 128;       // zeroed
    float* n2_cs  = ws + o;          o += 128;       // zeroed
    const size_t zero_bytes = o * sizeof(float);
    float* u1v    = ws + o;          o += 256;
    int*   off    = (int*)(ws + o);  o += M2;
    int*   pos_in = (int*)(ws + o);  o += NE;
    int*   pos_out= (int*)(ws + o);  o += NE;
    int*   lis    = (int*)(ws + o);  o += 2*NE;
    int*   btot   = (int*)(ws + o);  o += 400;

    u16* pbase = (u16*)(ws + o);
    size_t po = 0;
    u16* pWin1 = pbase + po;  po += (size_t)H1*H1;
    u16* pWout1= pbase + po;  po += (size_t)H1*H1;
    u16* pWn1  = pbase + po;  po += (size_t)FN*H1;
    u16* pWe1  = pbase + po;  po += (size_t)32*H1;   // K padded 16->32
    u16* pWe2  = pbase + po;  po += (size_t)H1*H2;
    u16* pWn2  = pbase + po;  po += (size_t)H1*H2;
    u16* pWin2 = pbase + po;  po += (size_t)H2*H2;
    u16* pWout2= pbase + po;  po += (size_t)H2*H2;
    o += (po + 1) / 2;

    u16* n1b = (u16*)(ws + o);       // NN*H1 bf16 = 25.6 MB

    float* n2_out = (float*)d_out;
    float* e2f    = n2_out + (size_t)NN*H2;          // e2 region; also scratch for e1 (bf16)
    float* u2_out = n2_out + (size_t)(NN + NE)*H2;
    u16*   e1b    = (u16*)e2f;                       // e1 bf16 rows live here until e2_kernel

    hipMemsetAsync(d_ws, 0, zero_bytes, stream);

    PackArgs pa;
    pa.d[0] = {Win1,  pWin1,  H1, H1, H1};
    pa.d[1] = {Wout1, pWout1, H1, H1, H1};
    pa.d[2] = {Wn1,   pWn1,   FN, H1, FN};
    pa.d[3] = {We1,   pWe1,   32, H1, FE};
    pa.d[4] = {We2,   pWe2,   H1, H2, H1};
    pa.d[5] = {Wn2,   pWn2,   H1, H2, H1};
    pa.d[6] = {Win2,  pWin2,  H2, H2, H2};
    pa.d[7] = {Wout2, pWout2, H2, H2, H2};
    int total_tiles = 0;
    for (int i = 0; i < 8; i++) total_tiles += (pa.d[i].K >> 5) * (pa.d[i].N >> 4);
    pack_weights<<<total_tiles, 64, 0, stream>>>(pa);

    const int EG = (NE + 255)/256;
    csr_count<<<EG, 256, 0, stream>>>(receivers, senders, cnt, pos_in, pos_out);
    scan_blocks<<<SCAN_B, 256, 0, stream>>>(cnt, off, btot);
    scan_tops<<<1, 256, 0, stream>>>(btot);
    scan_fix<<<SCAN_B, 256, 0, stream>>>(off, btot);
    csr_fill<<<EG, 256, 0, stream>>>(receivers, senders, off, pos_in, pos_out, lis);

    edge1_kernel<<<NE/64, 256, 0, stream>>>(edges, pWe1, be1, e1b, e1_cs);

    node1_kernel<<<(NN + 63)/64, 256, 0, stream>>>(nodes, e1b, off, lis,
        pWn1, pWin1, pWout1, bn1, n1b, n1_cs);

    u1_kernel<<<1, H1, 0, stream>>>(gu, Wu1, Wgn1, Wge1, bu1, n1_cs, e1_cs, u1v);

    e2_kernel<<<NE/64, 256, 0, stream>>>(e2f, pWe2, be2, e2_cs);

    node2_kernel<<<(NN + 63)/64, 256, 0, stream>>>(n1b, e2f, off, lis,
        pWn2, pWin2, pWout2, bn2, n2_out, n2_cs);

    u2_kernel<<<1, H2, 0, stream>>>(u1v, Wu2, Wgn2, Wge2, bu2, n2_cs, e2_cs, u2_out);
}